// Round 5
// baseline (287.735 us; speedup 1.0000x reference)
//
#include <hip/hip_runtime.h>
#include <hip/hip_bf16.h>

// ---------- constants ----------
#define M_ROWS   11520          // b*n = 2*5760
#define D_IN     512
#define HD       1960
#define HDP      2048           // padded hidden dim (multiple of 128); col = kk*40 + cch, kk=k1*7+k2
#define B2C      16
#define NVECS    720            // 20*36
#define LH       20
#define LW       36
#define HH       60
#define WW       108
#define CCH      40             // 1960/49
#define YSZ      (B2C * HH * WW * CCH)   // 4,147,200 f32, channel-last y

using bf16x8 = __attribute__((ext_vector_type(8))) short;
using f32x4  = __attribute__((ext_vector_type(4))) float;
using f4     = __attribute__((ext_vector_type(4))) float;
using su4    = __attribute__((ext_vector_type(4))) unsigned short;

__device__ __forceinline__ float bf2f(unsigned short u) {
    unsigned int x = ((unsigned int)u) << 16;
    return __builtin_bit_cast(float, x);
}
__device__ __forceinline__ unsigned short f2bf(float f) {
    unsigned int x = __builtin_bit_cast(unsigned int, f);
    unsigned int r = (x + 0x7fffu + ((x >> 16) & 1u)) >> 16;
    return (unsigned short)r;
}

// async global->LDS, 16 bytes per lane (global_load_lds_dwordx4)
__device__ __forceinline__ void gl_lds16(const unsigned short* g, unsigned short* l) {
    __builtin_amdgcn_global_load_lds(
        (const __attribute__((address_space(1))) unsigned int*)g,
        (__attribute__((address_space(3))) unsigned int*)l, 16, 0, 0);
}

// ---------- prep: conv x -> bf16, zero y, pack W1t / W2t in (kk,cch) order ----------
// zones: [0,5760) conv_x | [5760,9810) y zero | [9810,13906) W1t | [13906,18002) W2t
__global__ __launch_bounds__(256) void prep(
    const float* __restrict__ x, const float* __restrict__ W1, const float* __restrict__ W2,
    unsigned short* __restrict__ xb, unsigned short* __restrict__ w1t,
    unsigned short* __restrict__ w2t, float* __restrict__ y)
{
    int b = blockIdx.x, t = threadIdx.x;
    if (b < 5760) {                               // x (f32) -> xb (bf16), 4/thread
        int i = b * 256 + t;
        f4 v = ((const f4*)x)[i];
        su4 o;
        o.x = f2bf(v.x); o.y = f2bf(v.y); o.z = f2bf(v.z); o.w = f2bf(v.w);
        ((su4*)xb)[i] = o;
    } else if (b < 9810) {                        // zero y (4,147,200 f32)
        int i = (b - 5760) * 256 + t;
        ((f4*)y)[i] = (f4){0.f, 0.f, 0.f, 0.f};
    } else if (b < 13906) {                       // W1t[nn*512+k] = W1[k][perm(nn)]
        int i = (b - 9810) * 256 + t;             // 2048*512
        int nn = i >> 9, k = i & 511;
        unsigned short v = 0;
        if (nn < HD) {
            int kk = nn / CCH, cch = nn - kk * CCH;
            v = f2bf(W1[k * HD + cch * 49 + kk]);
        }
        w1t[i] = v;
    } else {                                      // W2t[n*2048+k] = W2[perm(k)][n]
        int i = (b - 13906) * 256 + t;            // 512*2048
        int n = i >> 11, k = i & 2047;
        unsigned short v = 0;
        int kk = k / CCH;
        if (kk < 49) {
            int cch = k - kk * CCH;
            v = f2bf(W2[(cch * 49 + kk) * 512 + n]);
        }
        w2t[i] = v;
    }
}

// ---------- GEMM1 + fold-scatter epilogue ----------
// h = x@W1 + b1 computed per 128x128 tile; each element scattered (atomicAdd f32)
// into channel-last y[b2][r][c][cch]. M=11520, N=2048, K=512, nbx=16.
__global__ __launch_bounds__(256) void gemm1_scatter(
    const unsigned short* __restrict__ A,
    const unsigned short* __restrict__ Bt,
    const float* __restrict__ bias,
    float* __restrict__ y)
{
    __shared__ unsigned short sA[128 * 32];
    __shared__ unsigned short sB[128 * 32];
    const int lda = D_IN, ldb = D_IN, K = D_IN, nbx = HDP / 128;

    int bid = blockIdx.x;
    int bx = bid % nbx, by = bid / nbx;
    int t    = threadIdx.x;
    int w    = t >> 6;
    int lane = t & 63;
    int quad = lane >> 4;
    int l16  = lane & 15;
    int row0 = by * 128, col0 = bx * 128;
    int wr = (w >> 1) * 64, wc = (w & 1) * 64;

    const unsigned short* Ag = A  + (size_t)(row0 + (t >> 2)) * lda + (t & 3) * 8;
    const unsigned short* Bg = Bt + (size_t)(col0 + (t >> 2)) * ldb + (t & 3) * 8;
    unsigned short* lA0 = sA + t * 8;
    unsigned short* lA1 = sA + 2048 + t * 8;
    unsigned short* lB0 = sB + t * 8;
    unsigned short* lB1 = sB + 2048 + t * 8;

    f32x4 acc[4][4] = {};

    for (int k0 = 0; k0 < K; k0 += 32) {
        gl_lds16(Ag + k0, lA0);
        gl_lds16(Ag + (size_t)64 * lda + k0, lA1);
        gl_lds16(Bg + k0, lB0);
        gl_lds16(Bg + (size_t)64 * ldb + k0, lB1);
        __syncthreads();

        bf16x8 a[4], bfr[4];
#pragma unroll
        for (int i = 0; i < 4; i++)
            a[i] = *(const bf16x8*)(sA + (wr + i * 16 + l16) * 32 + quad * 8);
#pragma unroll
        for (int j = 0; j < 4; j++)
            bfr[j] = *(const bf16x8*)(sB + (wc + j * 16 + l16) * 32 + quad * 8);
#pragma unroll
        for (int i = 0; i < 4; i++)
#pragma unroll
            for (int j = 0; j < 4; j++)
                acc[i][j] = __builtin_amdgcn_mfma_f32_16x16x32_bf16(a[i], bfr[j], acc[i][j], 0, 0, 0);
        __syncthreads();
    }

    // per-row spatial decode (16 rows this thread touches)
    int b2a[16], lha[16], lwa[16];
#pragma unroll
    for (int i = 0; i < 4; i++)
#pragma unroll
        for (int r = 0; r < 4; r++) {
            int row = row0 + wr + i * 16 + quad * 4 + r;
            int bb = row / NVECS;
            int v  = row - bb * NVECS;
            int lh = v / LW, lw = v - lh * LW;
            b2a[i * 4 + r] = bb; lha[i * 4 + r] = lh; lwa[i * 4 + r] = lw;
        }

#pragma unroll
    for (int j = 0; j < 4; j++) {
        int col = col0 + wc + j * 16 + l16;       // col = kk*40 + cch
        if (col < HD) {
            int kk  = col / CCH, cch = col - kk * CCH;
            int k1  = kk / 7,    k2  = kk - k1 * 7;
            float bv = bias[cch * 49 + kk];
#pragma unroll
            for (int i = 0; i < 4; i++)
#pragma unroll
                for (int r = 0; r < 4; r++) {
                    int e  = i * 4 + r;
                    int rr = 3 * lha[e] + k1 - 3;
                    int cc = 3 * lwa[e] + k2 - 3;
                    if ((unsigned)rr < (unsigned)HH && (unsigned)cc < (unsigned)WW) {
                        size_t idx = (((size_t)b2a[e] * HH + rr) * WW + cc) * CCH + cch;
                        unsafeAtomicAdd(&y[idx], acc[i][j][r] + bv);
                    }
                }
        }
    }
}

// ---------- unfold + norm + relu: y (f32 channel-last) -> uf (bf16, M x 2048) ----------
__global__ __launch_bounds__(256) void unfold_nr(
    const float* __restrict__ y, unsigned short* __restrict__ uf)
{
    int t = blockIdx.x * 256 + threadIdx.x;       // M_ROWS*512 threads, one su4 each
    int row = t >> 9;
    int c0  = (t & 511) << 2;                     // 4-aligned col, single kk group (40%4==0)
    su4 o = (su4){0, 0, 0, 0};
    int kk = c0 / CCH;
    if (kk < 49) {
        int cch0 = c0 - kk * CCH;
        int k1 = kk / 7, k2 = kk - k1 * 7;
        int b2 = row / NVECS, v = row - b2 * NVECS;
        int lh = v / LW, lw = v - lh * LW;
        int rr = 3 * lh + k1 - 3, cc = 3 * lw + k2 - 3;
        if ((unsigned)rr < (unsigned)HH && (unsigned)cc < (unsigned)WW) {
            f4 vy = *(const f4*)(y + (((size_t)b2 * HH + rr) * WW + cc) * CCH + cch0);
            int n1 = 0, n2 = 0;
            int rp = rr + 3, cp = cc + 3;
            for (int a = rp % 3; a < 7; a += 3) { int q = (rp - a) / 3; n1 += (q >= 0 && q < LH); }
            for (int a = cp % 3; a < 7; a += 3) { int q = (cp - a) / 3; n2 += (q >= 0 && q < LW); }
            float rn = 1.0f / (float)(n1 * n2);
            o.x = f2bf(fmaxf(vy.x, 0.f) * rn);
            o.y = f2bf(fmaxf(vy.y, 0.f) * rn);
            o.z = f2bf(fmaxf(vy.z, 0.f) * rn);
            o.w = f2bf(fmaxf(vy.w, 0.f) * rn);
        }
    }
    *(su4*)(uf + (size_t)row * HDP + c0) = o;
}

// ---------- GEMM2: out(f32) = uf @ W2t^T + b2 ----------
__global__ __launch_bounds__(256) void gemm2(
    const unsigned short* __restrict__ A,
    const unsigned short* __restrict__ Bt,
    const float* __restrict__ bias,
    float* __restrict__ C)
{
    __shared__ unsigned short sA[128 * 32];
    __shared__ unsigned short sB[128 * 32];
    const int lda = HDP, ldb = HDP, ldc = D_IN, K = HDP, nbx = D_IN / 128;

    int bid = blockIdx.x;
    int bx = bid % nbx, by = bid / nbx;
    int t    = threadIdx.x;
    int w    = t >> 6;
    int lane = t & 63;
    int quad = lane >> 4;
    int l16  = lane & 15;
    int row0 = by * 128, col0 = bx * 128;
    int wr = (w >> 1) * 64, wc = (w & 1) * 64;

    const unsigned short* Ag = A  + (size_t)(row0 + (t >> 2)) * lda + (t & 3) * 8;
    const unsigned short* Bg = Bt + (size_t)(col0 + (t >> 2)) * ldb + (t & 3) * 8;
    unsigned short* lA0 = sA + t * 8;
    unsigned short* lA1 = sA + 2048 + t * 8;
    unsigned short* lB0 = sB + t * 8;
    unsigned short* lB1 = sB + 2048 + t * 8;

    f32x4 acc[4][4] = {};

    for (int k0 = 0; k0 < K; k0 += 32) {
        gl_lds16(Ag + k0, lA0);
        gl_lds16(Ag + (size_t)64 * lda + k0, lA1);
        gl_lds16(Bg + k0, lB0);
        gl_lds16(Bg + (size_t)64 * ldb + k0, lB1);
        __syncthreads();

        bf16x8 a[4], bfr[4];
#pragma unroll
        for (int i = 0; i < 4; i++)
            a[i] = *(const bf16x8*)(sA + (wr + i * 16 + l16) * 32 + quad * 8);
#pragma unroll
        for (int j = 0; j < 4; j++)
            bfr[j] = *(const bf16x8*)(sB + (wc + j * 16 + l16) * 32 + quad * 8);
#pragma unroll
        for (int i = 0; i < 4; i++)
#pragma unroll
            for (int j = 0; j < 4; j++)
                acc[i][j] = __builtin_amdgcn_mfma_f32_16x16x32_bf16(a[i], bfr[j], acc[i][j], 0, 0, 0);
        __syncthreads();
    }

#pragma unroll
    for (int j = 0; j < 4; j++) {
        int col = col0 + wc + j * 16 + l16;
        float bv = bias[col];
#pragma unroll
        for (int i = 0; i < 4; i++) {
            int rbase = row0 + wr + i * 16 + quad * 4;
#pragma unroll
            for (int r = 0; r < 4; r++)
                C[(size_t)(rbase + r) * ldc + col] = acc[i][j][r] + bv;
        }
    }
}

// ---------- launch ----------
extern "C" void kernel_launch(void* const* d_in, const int* in_sizes, int n_in,
                              void* d_out, int out_size, void* d_ws, size_t ws_size,
                              hipStream_t stream) {
    const float* x   = (const float*)d_in[0];
    const float* W1  = (const float*)d_in[1];
    const float* b1  = (const float*)d_in[2];
    const float* W2  = (const float*)d_in[3];
    const float* b2f = (const float*)d_in[4];
    float* out = (float*)d_out;

    // workspace: y (f32) | w2t | uf ; xb & w1t alias the uf region (dead before uf written)
    float* y = (float*)d_ws;                                    // 4,147,200 f32
    unsigned short* w2t = (unsigned short*)(y + YSZ);           // 512*2048
    unsigned short* uf  = w2t + (size_t)D_IN * HDP;             // 11520*2048
    unsigned short* xb  = uf;                                   // 11520*512 (alias)
    unsigned short* w1t = xb + (size_t)M_ROWS * D_IN;           // 2048*512 (alias)

    // 1. prep: conv x, zero y, pack weights (1 dispatch)
    hipLaunchKernelGGL(prep, dim3(18002), dim3(256), 0, stream, x, W1, W2, xb, w1t, w2t, y);

    // 2. GEMM1 + fold scatter (atomicAdd into y)
    hipLaunchKernelGGL(gemm1_scatter, dim3((M_ROWS / 128) * (HDP / 128)), dim3(256), 0, stream,
                       xb, w1t, b1, y);

    // 3. unfold + norm + relu -> uf
    hipLaunchKernelGGL(unfold_nr, dim3(M_ROWS * 512 / 256), dim3(256), 0, stream, y, uf);

    // 4. GEMM2 -> out (f32)
    hipLaunchKernelGGL(gemm2, dim3((M_ROWS / 128) * (D_IN / 128)), dim3(256), 0, stream,
                       uf, w2t, b2f, out);
}

// Round 6
// 285.927 us; speedup vs baseline: 1.0063x; 1.0063x over previous
//
#include <hip/hip_runtime.h>
#include <hip/hip_bf16.h>

// ---------- constants ----------
#define M_ROWS   11520          // b*n = 2*5760
#define D_IN     512
#define HD       1960
#define HDP      2048           // padded N for GEMM1 tiles
#define CPAD     52             // per-cch padded patch count (49 -> 52)
#define K2       2080           // 40*52, GEMM2 K
#define B2C      16
#define NVECS    720            // 20*36
#define LH       20
#define LW       36
#define HH       60
#define WW       108
#define CCH      40             // 1960/49

using bf16x8 = __attribute__((ext_vector_type(8))) short;
using f32x4  = __attribute__((ext_vector_type(4))) float;
using f4     = __attribute__((ext_vector_type(4))) float;
using su4    = __attribute__((ext_vector_type(4))) unsigned short;

__device__ __forceinline__ float bf2f(unsigned short u) {
    unsigned int x = ((unsigned int)u) << 16;
    return __builtin_bit_cast(float, x);
}
__device__ __forceinline__ unsigned short f2bf(float f) {
    unsigned int x = __builtin_bit_cast(unsigned int, f);
    unsigned int r = (x + 0x7fffu + ((x >> 16) & 1u)) >> 16;
    return (unsigned short)r;
}

// async global->LDS, 16 bytes per lane (global_load_lds_dwordx4)
__device__ __forceinline__ void gl_lds16(const unsigned short* g, unsigned short* l) {
    __builtin_amdgcn_global_load_lds(
        (const __attribute__((address_space(1))) unsigned int*)g,
        (__attribute__((address_space(3))) unsigned int*)l, 16, 0, 0);
}

// ---------- prep: conv x -> bf16 | pack W1t (LDS transpose) | pack W2t (LDS transpose, 52-relabel) ----------
// zones: [0,5760) conv_x | [5760,6784) W1t (16 kt x 64 nt) | [6784,7776) W2t (62 kt x 16 nt)
__global__ __launch_bounds__(256) void prep(
    const float* __restrict__ x, const float* __restrict__ W1, const float* __restrict__ W2,
    unsigned short* __restrict__ xb, unsigned short* __restrict__ w1t,
    unsigned short* __restrict__ w2t)
{
    __shared__ unsigned short tile[32][33];
    int b = blockIdx.x, t = threadIdx.x;
    if (b < 5760) {                               // x (f32) -> xb (bf16), 4/thread
        int i = b * 256 + t;
        f4 v = ((const f4*)x)[i];
        su4 o;
        o.x = f2bf(v.x); o.y = f2bf(v.y); o.z = f2bf(v.z); o.w = f2bf(v.w);
        ((su4*)xb)[i] = o;
        return;
    }
    int tx = t & 31, ty = t >> 5;                 // ty in [0,8)
    if (b < 6784) {                               // W1t[n*512+k] = W1[k*1960+n], pad n>=1960 -> 0
        int blk = b - 5760;
        int kt = blk & 15, nt = blk >> 4;
        int k0 = kt * 32, n0 = nt * 32;
#pragma unroll
        for (int p = 0; p < 4; p++) {
            int k = k0 + ty + p * 8;
            int n = n0 + tx;
            tile[ty + p * 8][tx] = (n < HD) ? f2bf(W1[k * HD + n]) : (unsigned short)0;
        }
        __syncthreads();
#pragma unroll
        for (int p = 0; p < 4; p++) {
            int n = n0 + ty + p * 8;
            int k = k0 + tx;
            w1t[n * 512 + k] = tile[tx][ty + p * 8];
        }
    } else {                                      // W2t[n*2080 + cch*52+kk] = W2[(cch*49+kk)*512+n]
        int blk = b - 6784;                       // 62 kt x 16 nt
        int kt = blk % 62, nt = blk / 62;
        int k0 = kt * 32, n0 = nt * 32;
#pragma unroll
        for (int p = 0; p < 4; p++) {
            int k = k0 + ty + p * 8;
            int n = n0 + tx;
            tile[ty + p * 8][tx] = (k < HD) ? f2bf(W2[k * 512 + n]) : (unsigned short)0;
        }
        __syncthreads();
#pragma unroll
        for (int p = 0; p < 4; p++) {
            int n = n0 + ty + p * 8;
            int k = k0 + tx;
            if (k < HD) {
                int cch = k / 49, kk = k - cch * 49;
                w2t[n * K2 + cch * CPAD + kk] = tile[tx][ty + p * 8];
            }
        }
    }
}

// ---------- GEMM1: h_blk[(b2*40+cch)*720 + sp][52] = x @ W1 + b1 (blocked-layout epilogue) ----------
__global__ __launch_bounds__(256) void gemm1_blk(
    const unsigned short* __restrict__ A,
    const unsigned short* __restrict__ Bt,
    const float* __restrict__ bias,
    unsigned short* __restrict__ h_blk)
{
    __shared__ unsigned short sA[128 * 32];
    __shared__ unsigned short sB[128 * 32];
    const int lda = D_IN, ldb = D_IN, K = D_IN, nbx = HDP / 128;

    int bid = blockIdx.x;
    int bx = bid % nbx, by = bid / nbx;
    int t    = threadIdx.x;
    int w    = t >> 6;
    int lane = t & 63;
    int quad = lane >> 4;
    int l16  = lane & 15;
    int row0 = by * 128, col0 = bx * 128;
    int wr = (w >> 1) * 64, wc = (w & 1) * 64;

    const unsigned short* Ag = A  + (size_t)(row0 + (t >> 2)) * lda + (t & 3) * 8;
    const unsigned short* Bg = Bt + (size_t)(col0 + (t >> 2)) * ldb + (t & 3) * 8;
    unsigned short* lA0 = sA + t * 8;
    unsigned short* lA1 = sA + 2048 + t * 8;
    unsigned short* lB0 = sB + t * 8;
    unsigned short* lB1 = sB + 2048 + t * 8;

    f32x4 acc[4][4] = {};

    for (int k0 = 0; k0 < K; k0 += 32) {
        gl_lds16(Ag + k0, lA0);
        gl_lds16(Ag + (size_t)64 * lda + k0, lA1);
        gl_lds16(Bg + k0, lB0);
        gl_lds16(Bg + (size_t)64 * ldb + k0, lB1);
        __syncthreads();

        bf16x8 a[4], bfr[4];
#pragma unroll
        for (int i = 0; i < 4; i++)
            a[i] = *(const bf16x8*)(sA + (wr + i * 16 + l16) * 32 + quad * 8);
#pragma unroll
        for (int j = 0; j < 4; j++)
            bfr[j] = *(const bf16x8*)(sB + (wc + j * 16 + l16) * 32 + quad * 8);
#pragma unroll
        for (int i = 0; i < 4; i++)
#pragma unroll
            for (int j = 0; j < 4; j++)
                acc[i][j] = __builtin_amdgcn_mfma_f32_16x16x32_bf16(a[i], bfr[j], acc[i][j], 0, 0, 0);
        __syncthreads();
    }

    // row terms: addr = b2*1497600 + cch*37440 + sp*52 + kk
    int rowterm[16];
#pragma unroll
    for (int i = 0; i < 4; i++)
#pragma unroll
        for (int r = 0; r < 4; r++) {
            int row = row0 + wr + i * 16 + quad * 4 + r;
            int bb = row / NVECS;
            int sp = row - bb * NVECS;
            rowterm[i * 4 + r] = bb * (CCH * NVECS * CPAD) + sp * CPAD;
        }

#pragma unroll
    for (int j = 0; j < 4; j++) {
        int col = col0 + wc + j * 16 + l16;       // natural: col = cch*49 + kk
        if (col < HD) {
            int cch = col / 49, kk = col - cch * 49;
            int colterm = cch * (NVECS * CPAD) + kk;
            float bv = bias[col];
#pragma unroll
            for (int i = 0; i < 4; i++)
#pragma unroll
                for (int r = 0; r < 4; r++)
                    h_blk[(size_t)rowterm[i * 4 + r] + colterm] = f2bf(acc[i][j][r] + bv);
        }
    }
}

// ---------- fold + normalize: h_blk -> y (bf16, [b2][cch][60][108]) ----------
// block = (b2, cch, p): y rows [15p,15p+15); stages contiguous h_blk strip lh in [5p-1,5p+6)
__global__ __launch_bounds__(256) void fold_y(
    const unsigned short* __restrict__ h_blk,
    unsigned short* __restrict__ y)
{
    __shared__ unsigned short h_lds[7 * 36 * CPAD];   // 26,208 B
    int bid = blockIdx.x;                             // 16*40*4 = 2560
    int p   = bid & 3;
    int cch = (bid >> 2) % CCH;
    int b2  = bid / (CCH * 4);
    int tid = threadIdx.x;

    int lh_base = 5 * p - 1;
    int lh_lo = lh_base < 0 ? 0 : lh_base;
    int lh_hi = 5 * p + 6; if (lh_hi > LH) lh_hi = LH;
    int slot0 = lh_lo - lh_base;
    int nrows = lh_hi - lh_lo;                        // strip rows (of 36*52 elems each)

    const su4* hsrc = (const su4*)(h_blk + (size_t)(b2 * CCH + cch) * (NVECS * CPAD) + lh_lo * (36 * CPAD));
    su4* ldst = (su4*)(h_lds + slot0 * (36 * CPAD));
    int total4 = nrows * (36 * CPAD / 4);             // su4 count, contiguous
    for (int i = tid; i < total4; i += 256)
        ldst[i] = hsrc[i];
    __syncthreads();

    unsigned short* yb = y + ((size_t)(b2 * CCH + cch) * HH + 15 * p) * WW;
    for (int idx = tid; idx < 15 * WW; idx += 256) {
        int rr = idx / WW, c = idx - rr * WW;
        int r = 15 * p + rr;
        int rp = r + 3, cp = c + 3;
        int n1 = 0, n2 = 0;
        int sl_v[3], k1_v[3], lw_v[3], k2_v[3];
        for (int k1 = rp % 3; k1 < 7; k1 += 3) {
            int lh = (rp - k1) / 3;
            if (lh >= 0 && lh < LH) { sl_v[n1] = lh - lh_base; k1_v[n1] = k1; n1++; }
        }
        for (int k2 = cp % 3; k2 < 7; k2 += 3) {
            int lw = (cp - k2) / 3;
            if (lw >= 0 && lw < LW) { lw_v[n2] = lw; k2_v[n2] = k2; n2++; }
        }
        float s = 0.0f;
        for (int i = 0; i < n1; i++)
            for (int j = 0; j < n2; j++)
                s += bf2f(h_lds[(sl_v[i] * 36 + lw_v[j]) * CPAD + k1_v[i] * 7 + k2_v[j]]);
        yb[(size_t)rr * WW + c] = f2bf(s / (float)(n1 * n2));
    }
}

// ---------- unfold + relu into 52-padded layout: y -> uf (M x 2080) ----------
__global__ void unfold_relu52(const unsigned short* __restrict__ y,
                              unsigned short* __restrict__ uf) {
    int t = blockIdx.x * 256 + threadIdx.x;       // total M_ROWS*520 (one su4 each)
    int row = t / 520;
    int q = t - row * 520;
    int cch = q / 13;
    int j0 = (q - cch * 13) * 4;
    int b2 = row / NVECS;
    int v  = row - b2 * NVECS;
    int lh = v / LW, lw = v - lh * LW;
    int rb = 3 * lh - 3, cb = 3 * lw - 3;
    const unsigned short* yb = y + (size_t)(b2 * CCH + cch) * HH * WW;

    su4 o;
#pragma unroll
    for (int e = 0; e < 4; e++) {
        int j = j0 + e;
        unsigned short val = 0;
        if (j < 49) {
            int k1 = j / 7, k2 = j - k1 * 7;
            int r = rb + k1, cc = cb + k2;
            if ((unsigned)r < (unsigned)HH && (unsigned)cc < (unsigned)WW) {
                unsigned short u = yb[r * WW + cc];
                val = (u & 0x8000u) ? (unsigned short)0 : u;
            }
        }
        ((unsigned short*)&o)[e] = val;
    }
    *(su4*)(uf + (size_t)row * K2 + q * 4) = o;
}

// ---------- GEMM2: out(f32) = uf @ W2t^T + b2   (M=11520, N=512, K=2080) ----------
__global__ __launch_bounds__(256) void gemm2(
    const unsigned short* __restrict__ A,
    const unsigned short* __restrict__ Bt,
    const float* __restrict__ bias,
    float* __restrict__ C)
{
    __shared__ unsigned short sA[128 * 32];
    __shared__ unsigned short sB[128 * 32];
    const int lda = K2, ldb = K2, ldc = D_IN, K = K2, nbx = D_IN / 128;

    int bid = blockIdx.x;
    int bx = bid % nbx, by = bid / nbx;
    int t    = threadIdx.x;
    int w    = t >> 6;
    int lane = t & 63;
    int quad = lane >> 4;
    int l16  = lane & 15;
    int row0 = by * 128, col0 = bx * 128;
    int wr = (w >> 1) * 64, wc = (w & 1) * 64;

    const unsigned short* Ag = A  + (size_t)(row0 + (t >> 2)) * lda + (t & 3) * 8;
    const unsigned short* Bg = Bt + (size_t)(col0 + (t >> 2)) * ldb + (t & 3) * 8;
    unsigned short* lA0 = sA + t * 8;
    unsigned short* lA1 = sA + 2048 + t * 8;
    unsigned short* lB0 = sB + t * 8;
    unsigned short* lB1 = sB + 2048 + t * 8;

    f32x4 acc[4][4] = {};

    for (int k0 = 0; k0 < K; k0 += 32) {
        gl_lds16(Ag + k0, lA0);
        gl_lds16(Ag + (size_t)64 * lda + k0, lA1);
        gl_lds16(Bg + k0, lB0);
        gl_lds16(Bg + (size_t)64 * ldb + k0, lB1);
        __syncthreads();

        bf16x8 a[4], bfr[4];
#pragma unroll
        for (int i = 0; i < 4; i++)
            a[i] = *(const bf16x8*)(sA + (wr + i * 16 + l16) * 32 + quad * 8);
#pragma unroll
        for (int j = 0; j < 4; j++)
            bfr[j] = *(const bf16x8*)(sB + (wc + j * 16 + l16) * 32 + quad * 8);
#pragma unroll
        for (int i = 0; i < 4; i++)
#pragma unroll
            for (int j = 0; j < 4; j++)
                acc[i][j] = __builtin_amdgcn_mfma_f32_16x16x32_bf16(a[i], bfr[j], acc[i][j], 0, 0, 0);
        __syncthreads();
    }

#pragma unroll
    for (int j = 0; j < 4; j++) {
        int col = col0 + wc + j * 16 + l16;
        float bv = bias[col];
#pragma unroll
        for (int i = 0; i < 4; i++) {
            int rbase = row0 + wr + i * 16 + quad * 4;
#pragma unroll
            for (int r = 0; r < 4; r++)
                C[(size_t)(rbase + r) * ldc + col] = acc[i][j][r] + bv;
        }
    }
}

// ---------- launch ----------
extern "C" void kernel_launch(void* const* d_in, const int* in_sizes, int n_in,
                              void* d_out, int out_size, void* d_ws, size_t ws_size,
                              hipStream_t stream) {
    const float* x   = (const float*)d_in[0];
    const float* W1  = (const float*)d_in[1];
    const float* b1  = (const float*)d_in[2];
    const float* W2  = (const float*)d_in[3];
    const float* b2f = (const float*)d_in[4];
    float* out = (float*)d_out;

    unsigned short* ws   = (unsigned short*)d_ws;
    unsigned short* xb   = ws;                                  // 11520*512
    unsigned short* h_uf = xb + (size_t)M_ROWS * D_IN;          // 23,961,600 (h_blk, then uf — same size)
    unsigned short* y    = h_uf + (size_t)M_ROWS * K2;          // 4,147,200
    unsigned short* w1t  = y + (size_t)B2C * CCH * HH * WW;     // 2048*512
    unsigned short* w2t  = w1t + (size_t)HDP * D_IN;            // 512*2080

    // 1. prep: conv x, pack W1t, pack W2t (one dispatch)
    hipLaunchKernelGGL(prep, dim3(7776), dim3(256), 0, stream, x, W1, W2, xb, w1t, w2t);

    // 2. GEMM1 -> h_blk (blocked fold-friendly layout)
    hipLaunchKernelGGL(gemm1_blk, dim3((M_ROWS / 128) * (HDP / 128)), dim3(256), 0, stream,
                       xb, w1t, b1, h_uf);

    // 3. fold + normalize -> y
    hipLaunchKernelGGL(fold_y, dim3(B2C * CCH * 4), dim3(256), 0, stream, h_uf, y);

    // 4. unfold + relu -> uf (52-padded, overwrites h_blk)
    hipLaunchKernelGGL(unfold_relu52, dim3(M_ROWS * 520 / 256), dim3(256), 0, stream, y, h_uf);

    // 5. GEMM2 -> out (f32)
    hipLaunchKernelGGL(gemm2, dim3((M_ROWS / 128) * (D_IN / 128)), dim3(256), 0, stream,
                       h_uf, w2t, b2f, out);
}

// Round 7
// 265.840 us; speedup vs baseline: 1.0824x; 1.0756x over previous
//
#include <hip/hip_runtime.h>
#include <hip/hip_bf16.h>

// ---------- constants ----------
#define M_ROWS   11520          // b*n = 2*5760
#define D_IN     512
#define HD       1960
#define HDP      2048           // padded N for GEMM1 tiles
#define CPAD     52             // per-cch padded patch count (49 -> 52)
#define K2       2080           // 40*52, GEMM2 K
#define B2C      16
#define NVECS    720            // 20*36
#define LH       20
#define LW       36
#define HH       60
#define WW       108
#define CCH      40             // 1960/49

using bf16x8 = __attribute__((ext_vector_type(8))) short;
using f32x4  = __attribute__((ext_vector_type(4))) float;
using f4     = __attribute__((ext_vector_type(4))) float;
using su4    = __attribute__((ext_vector_type(4))) unsigned short;

__device__ __forceinline__ float bf2f(unsigned short u) {
    unsigned int x = ((unsigned int)u) << 16;
    return __builtin_bit_cast(float, x);
}
__device__ __forceinline__ unsigned short f2bf(float f) {
    unsigned int x = __builtin_bit_cast(unsigned int, f);
    unsigned int r = (x + 0x7fffu + ((x >> 16) & 1u)) >> 16;
    return (unsigned short)r;
}

// async global->LDS, 16 bytes per lane (global_load_lds_dwordx4)
__device__ __forceinline__ void gl_lds16(const unsigned short* g, unsigned short* l) {
    __builtin_amdgcn_global_load_lds(
        (const __attribute__((address_space(1))) unsigned int*)g,
        (__attribute__((address_space(3))) unsigned int*)l, 16, 0, 0);
}

// ---------- prep: conv x -> bf16 | pack W1t (LDS transpose) | pack W2t (LDS transpose, 52-relabel) ----------
// zones: [0,5760) conv_x | [5760,6784) W1t (16 kt x 64 nt) | [6784,7776) W2t (62 kt x 16 nt)
__global__ __launch_bounds__(256) void prep(
    const float* __restrict__ x, const float* __restrict__ W1, const float* __restrict__ W2,
    unsigned short* __restrict__ xb, unsigned short* __restrict__ w1t,
    unsigned short* __restrict__ w2t)
{
    __shared__ unsigned short tile[32][33];
    int b = blockIdx.x, t = threadIdx.x;
    if (b < 5760) {                               // x (f32) -> xb (bf16), 4/thread
        int i = b * 256 + t;
        f4 v = ((const f4*)x)[i];
        su4 o;
        o.x = f2bf(v.x); o.y = f2bf(v.y); o.z = f2bf(v.z); o.w = f2bf(v.w);
        ((su4*)xb)[i] = o;
        return;
    }
    int tx = t & 31, ty = t >> 5;                 // ty in [0,8)
    if (b < 6784) {                               // W1t[n*512+k] = W1[k*1960+n], pad n>=1960 -> 0
        int blk = b - 5760;
        int kt = blk & 15, nt = blk >> 4;
        int k0 = kt * 32, n0 = nt * 32;
#pragma unroll
        for (int p = 0; p < 4; p++) {
            int k = k0 + ty + p * 8;
            int n = n0 + tx;
            tile[ty + p * 8][tx] = (n < HD) ? f2bf(W1[k * HD + n]) : (unsigned short)0;
        }
        __syncthreads();
#pragma unroll
        for (int p = 0; p < 4; p++) {
            int n = n0 + ty + p * 8;
            int k = k0 + tx;
            w1t[n * 512 + k] = tile[tx][ty + p * 8];
        }
    } else {                                      // W2t[n*2080 + cch*52+kk] = W2[(cch*49+kk)*512+n]
        int blk = b - 6784;                       // 62 kt x 16 nt
        int kt = blk % 62, nt = blk / 62;
        int k0 = kt * 32, n0 = nt * 32;
#pragma unroll
        for (int p = 0; p < 4; p++) {
            int k = k0 + ty + p * 8;
            int n = n0 + tx;
            tile[ty + p * 8][tx] = (k < HD) ? f2bf(W2[k * 512 + n]) : (unsigned short)0;
        }
        __syncthreads();
#pragma unroll
        for (int p = 0; p < 4; p++) {
            int n = n0 + ty + p * 8;
            int k = k0 + tx;
            if (k < HD) {
                int cch = k / 49, kk = k - cch * 49;
                w2t[n * K2 + cch * CPAD + kk] = tile[tx][ty + p * 8];
            }
        }
    }
}

// ---------- GEMM1: h_blk[(b2*40+cch)*720 + sp][52] = x @ W1 + b1 (blocked-layout epilogue) ----------
__global__ __launch_bounds__(256) void gemm1_blk(
    const unsigned short* __restrict__ A,
    const unsigned short* __restrict__ Bt,
    const float* __restrict__ bias,
    unsigned short* __restrict__ h_blk)
{
    __shared__ unsigned short sA[128 * 32];
    __shared__ unsigned short sB[128 * 32];
    const int lda = D_IN, ldb = D_IN, K = D_IN, nbx = HDP / 128;

    int bid = blockIdx.x;
    int bx = bid % nbx, by = bid / nbx;
    int t    = threadIdx.x;
    int w    = t >> 6;
    int lane = t & 63;
    int quad = lane >> 4;
    int l16  = lane & 15;
    int row0 = by * 128, col0 = bx * 128;
    int wr = (w >> 1) * 64, wc = (w & 1) * 64;

    const unsigned short* Ag = A  + (size_t)(row0 + (t >> 2)) * lda + (t & 3) * 8;
    const unsigned short* Bg = Bt + (size_t)(col0 + (t >> 2)) * ldb + (t & 3) * 8;
    unsigned short* lA0 = sA + t * 8;
    unsigned short* lA1 = sA + 2048 + t * 8;
    unsigned short* lB0 = sB + t * 8;
    unsigned short* lB1 = sB + 2048 + t * 8;

    f32x4 acc[4][4] = {};

    for (int k0 = 0; k0 < K; k0 += 32) {
        gl_lds16(Ag + k0, lA0);
        gl_lds16(Ag + (size_t)64 * lda + k0, lA1);
        gl_lds16(Bg + k0, lB0);
        gl_lds16(Bg + (size_t)64 * ldb + k0, lB1);
        __syncthreads();

        bf16x8 a[4], bfr[4];
#pragma unroll
        for (int i = 0; i < 4; i++)
            a[i] = *(const bf16x8*)(sA + (wr + i * 16 + l16) * 32 + quad * 8);
#pragma unroll
        for (int j = 0; j < 4; j++)
            bfr[j] = *(const bf16x8*)(sB + (wc + j * 16 + l16) * 32 + quad * 8);
#pragma unroll
        for (int i = 0; i < 4; i++)
#pragma unroll
            for (int j = 0; j < 4; j++)
                acc[i][j] = __builtin_amdgcn_mfma_f32_16x16x32_bf16(a[i], bfr[j], acc[i][j], 0, 0, 0);
        __syncthreads();
    }

    // row terms: addr = b2*1497600 + cch*37440 + sp*52 + kk
    int rowterm[16];
#pragma unroll
    for (int i = 0; i < 4; i++)
#pragma unroll
        for (int r = 0; r < 4; r++) {
            int row = row0 + wr + i * 16 + quad * 4 + r;
            int bb = row / NVECS;
            int sp = row - bb * NVECS;
            rowterm[i * 4 + r] = bb * (CCH * NVECS * CPAD) + sp * CPAD;
        }

#pragma unroll
    for (int j = 0; j < 4; j++) {
        int col = col0 + wc + j * 16 + l16;       // natural: col = cch*49 + kk
        if (col < HD) {
            int cch = col / 49, kk = col - cch * 49;
            int colterm = cch * (NVECS * CPAD) + kk;
            float bv = bias[col];
#pragma unroll
            for (int i = 0; i < 4; i++)
#pragma unroll
                for (int r = 0; r < 4; r++)
                    h_blk[(size_t)rowterm[i * 4 + r] + colterm] = f2bf(acc[i][j][r] + bv);
        }
    }
}

// ---------- fused fold+norm+relu+unfold: h_blk -> uf (M x 2080, 52-padded) ----------
// block = (b2, cch, half): stages h_blk lh-rows [8*half, 8*half+12) -> LDS,
// computes y rows [27*half, 27*half + (half?33:31)) in LDS (norm+relu applied),
// then unfold-gathers rows lh in [10*half, 10*half+10) and writes uf.
__global__ __launch_bounds__(256) void fold_unfold(
    const unsigned short* __restrict__ h_blk,
    unsigned short* __restrict__ uf)
{
    __shared__ unsigned short h_lds[12 * 36 * CPAD];  // 44,928 B
    __shared__ unsigned short y_lds[33 * WW];         //  7,128 B
    int bid  = blockIdx.x;                            // 16*40*2 = 1280
    int half = bid & 1;
    int cch  = (bid >> 1) % CCH;
    int b2   = bid / (CCH * 2);
    int tid  = threadIdx.x;

    int lh_base = half ? 8 : 0;
    int y0 = half ? 27 : 0;
    int ny = half ? 33 : 31;

    // stage 12 contiguous lh-strips of h_blk
    const su4* hsrc = (const su4*)(h_blk +
        ((size_t)(b2 * CCH + cch) * NVECS + lh_base * 36) * CPAD);
    su4* hd = (su4*)h_lds;
    for (int i = tid; i < 12 * 36 * CPAD / 4; i += 256)
        hd[i] = hsrc[i];
    __syncthreads();

    // fold + normalize + relu into y_lds
    for (int idx = tid; idx < ny * WW; idx += 256) {
        int rr = idx / WW, c = idx - rr * WW;
        int r = y0 + rr;
        int rp = r + 3, cp = c + 3;
        int n1 = 0, n2 = 0;
        int sl_v[3], k1_v[3], lw_v[3], k2_v[3];
        for (int k1 = rp % 3; k1 < 7; k1 += 3) {
            int lh = (rp - k1) / 3;
            if (lh >= 0 && lh < LH) { sl_v[n1] = lh - lh_base; k1_v[n1] = k1; n1++; }
        }
        for (int k2 = cp % 3; k2 < 7; k2 += 3) {
            int lw = (cp - k2) / 3;
            if (lw >= 0 && lw < LW) { lw_v[n2] = lw; k2_v[n2] = k2; n2++; }
        }
        float s = 0.0f;
        for (int i = 0; i < n1; i++)
            for (int j = 0; j < n2; j++)
                s += bf2f(h_lds[(sl_v[i] * 36 + lw_v[j]) * CPAD + k1_v[i] * 7 + k2_v[j]]);
        y_lds[idx] = f2bf(fmaxf(s / (float)(n1 * n2), 0.0f));
    }
    __syncthreads();

    // unfold: 360 rows (lh in [10*half, 10*half+10) x lw in [0,36)), 13 su4 each
    int lh0 = 10 * half;
    for (int i = tid; i < 360 * 13; i += 256) {
        int ri = i / 13, q = i - ri * 13;
        int lh = lh0 + ri / 36;
        int lw = ri % 36;
        int rb = 3 * lh - 3, cb = 3 * lw - 3;
        int j0 = q * 4;
        su4 o;
#pragma unroll
        for (int e = 0; e < 4; e++) {
            int j = j0 + e;
            unsigned short val = 0;
            if (j < 49) {
                int k1 = j / 7, k2 = j - k1 * 7;
                int r = rb + k1, cc = cb + k2;
                if ((unsigned)r < (unsigned)HH && (unsigned)cc < (unsigned)WW)
                    val = y_lds[(r - y0) * WW + cc];
            }
            ((unsigned short*)&o)[e] = val;
        }
        int row = b2 * NVECS + lh * 36 + lw;
        *(su4*)(uf + (size_t)row * K2 + cch * CPAD + j0) = o;
    }
}

// ---------- GEMM2: out(f32) = uf @ W2t^T + b2   (M=11520, N=512, K=2080) ----------
__global__ __launch_bounds__(256) void gemm2(
    const unsigned short* __restrict__ A,
    const unsigned short* __restrict__ Bt,
    const float* __restrict__ bias,
    float* __restrict__ C)
{
    __shared__ unsigned short sA[128 * 32];
    __shared__ unsigned short sB[128 * 32];
    const int lda = K2, ldb = K2, ldc = D_IN, K = K2, nbx = D_IN / 128;

    int bid = blockIdx.x;
    int bx = bid % nbx, by = bid / nbx;
    int t    = threadIdx.x;
    int w    = t >> 6;
    int lane = t & 63;
    int quad = lane >> 4;
    int l16  = lane & 15;
    int row0 = by * 128, col0 = bx * 128;
    int wr = (w >> 1) * 64, wc = (w & 1) * 64;

    const unsigned short* Ag = A  + (size_t)(row0 + (t >> 2)) * lda + (t & 3) * 8;
    const unsigned short* Bg = Bt + (size_t)(col0 + (t >> 2)) * ldb + (t & 3) * 8;
    unsigned short* lA0 = sA + t * 8;
    unsigned short* lA1 = sA + 2048 + t * 8;
    unsigned short* lB0 = sB + t * 8;
    unsigned short* lB1 = sB + 2048 + t * 8;

    f32x4 acc[4][4] = {};

    for (int k0 = 0; k0 < K; k0 += 32) {
        gl_lds16(Ag + k0, lA0);
        gl_lds16(Ag + (size_t)64 * lda + k0, lA1);
        gl_lds16(Bg + k0, lB0);
        gl_lds16(Bg + (size_t)64 * ldb + k0, lB1);
        __syncthreads();

        bf16x8 a[4], bfr[4];
#pragma unroll
        for (int i = 0; i < 4; i++)
            a[i] = *(const bf16x8*)(sA + (wr + i * 16 + l16) * 32 + quad * 8);
#pragma unroll
        for (int j = 0; j < 4; j++)
            bfr[j] = *(const bf16x8*)(sB + (wc + j * 16 + l16) * 32 + quad * 8);
#pragma unroll
        for (int i = 0; i < 4; i++)
#pragma unroll
            for (int j = 0; j < 4; j++)
                acc[i][j] = __builtin_amdgcn_mfma_f32_16x16x32_bf16(a[i], bfr[j], acc[i][j], 0, 0, 0);
        __syncthreads();
    }

#pragma unroll
    for (int j = 0; j < 4; j++) {
        int col = col0 + wc + j * 16 + l16;
        float bv = bias[col];
#pragma unroll
        for (int i = 0; i < 4; i++) {
            int rbase = row0 + wr + i * 16 + quad * 4;
#pragma unroll
            for (int r = 0; r < 4; r++)
                C[(size_t)(rbase + r) * ldc + col] = acc[i][j][r] + bv;
        }
    }
}

// ---------- launch ----------
extern "C" void kernel_launch(void* const* d_in, const int* in_sizes, int n_in,
                              void* d_out, int out_size, void* d_ws, size_t ws_size,
                              hipStream_t stream) {
    const float* x   = (const float*)d_in[0];
    const float* W1  = (const float*)d_in[1];
    const float* b1  = (const float*)d_in[2];
    const float* W2  = (const float*)d_in[3];
    const float* b2f = (const float*)d_in[4];
    float* out = (float*)d_out;

    unsigned short* ws   = (unsigned short*)d_ws;
    unsigned short* xb   = ws;                                  // 11520*512
    unsigned short* h_blk = xb + (size_t)M_ROWS * D_IN;         // 23,961,600 (h_blk)
    unsigned short* uf   = h_blk + (size_t)M_ROWS * K2;         // 23,961,600 (uf, separate)
    unsigned short* w1t  = uf + (size_t)M_ROWS * K2;            // 2048*512
    unsigned short* w2t  = w1t + (size_t)HDP * D_IN;            // 512*2080

    // 1. prep: conv x, pack W1t, pack W2t (one dispatch)
    hipLaunchKernelGGL(prep, dim3(7776), dim3(256), 0, stream, x, W1, W2, xb, w1t, w2t);

    // 2. GEMM1 -> h_blk (blocked fold-friendly layout)
    hipLaunchKernelGGL(gemm1_blk, dim3((M_ROWS / 128) * (HDP / 128)), dim3(256), 0, stream,
                       xb, w1t, b1, h_blk);

    // 3. fused fold + normalize + relu + unfold -> uf (52-padded)
    hipLaunchKernelGGL(fold_unfold, dim3(B2C * CCH * 2), dim3(256), 0, stream, h_blk, uf);

    // 4. GEMM2 -> out (f32)
    hipLaunchKernelGGL(gemm2, dim3((M_ROWS / 128) * (D_IN / 128)), dim3(256), 0, stream,
                       uf, w2t, b2f, out);
}

// Round 8
// 246.299 us; speedup vs baseline: 1.1682x; 1.0793x over previous
//
#include <hip/hip_runtime.h>
#include <hip/hip_bf16.h>

// ---------- constants ----------
#define M_ROWS   11520          // b*n = 2*5760
#define D_IN     512
#define HD       1960
#define HDP      2048           // padded N for GEMM1 tiles
#define CPAD     52             // per-cch padded patch count (49 -> 52)
#define K2       2080           // 40*52, GEMM2 K
#define B2C      16
#define NVECS    720            // 20*36
#define LH       20
#define LW       36
#define HH       60
#define WW       108
#define CCH      40             // 1960/49

using bf16x8 = __attribute__((ext_vector_type(8))) short;
using f32x4  = __attribute__((ext_vector_type(4))) float;
using f4     = __attribute__((ext_vector_type(4))) float;
using su4    = __attribute__((ext_vector_type(4))) unsigned short;

__device__ __forceinline__ float bf2f(unsigned short u) {
    unsigned int x = ((unsigned int)u) << 16;
    return __builtin_bit_cast(float, x);
}
__device__ __forceinline__ unsigned short f2bf(float f) {
    unsigned int x = __builtin_bit_cast(unsigned int, f);
    unsigned int r = (x + 0x7fffu + ((x >> 16) & 1u)) >> 16;
    return (unsigned short)r;
}

// async global->LDS, 16 bytes per lane (global_load_lds_dwordx4)
__device__ __forceinline__ void gl_lds16(const unsigned short* g, unsigned short* l) {
    __builtin_amdgcn_global_load_lds(
        (const __attribute__((address_space(1))) unsigned int*)g,
        (__attribute__((address_space(3))) unsigned int*)l, 16, 0, 0);
}

// ---------- prep: conv x -> bf16 | pack W1t (LDS transpose) | pack W2t (LDS transpose, 52-relabel) ----------
// zones: [0,5760) conv_x | [5760,6784) W1t (16 kt x 64 nt) | [6784,7776) W2t (62 kt x 16 nt)
__global__ __launch_bounds__(256) void prep(
    const float* __restrict__ x, const float* __restrict__ W1, const float* __restrict__ W2,
    unsigned short* __restrict__ xb, unsigned short* __restrict__ w1t,
    unsigned short* __restrict__ w2t)
{
    __shared__ unsigned short tile[32][33];
    int b = blockIdx.x, t = threadIdx.x;
    if (b < 5760) {                               // x (f32) -> xb (bf16), 4/thread
        int i = b * 256 + t;
        f4 v = ((const f4*)x)[i];
        su4 o;
        o.x = f2bf(v.x); o.y = f2bf(v.y); o.z = f2bf(v.z); o.w = f2bf(v.w);
        ((su4*)xb)[i] = o;
        return;
    }
    int tx = t & 31, ty = t >> 5;                 // ty in [0,8)
    if (b < 6784) {                               // W1t[n*512+k] = W1[k*1960+n], pad n>=1960 -> 0
        int blk = b - 5760;
        int kt = blk & 15, nt = blk >> 4;
        int k0 = kt * 32, n0 = nt * 32;
#pragma unroll
        for (int p = 0; p < 4; p++) {
            int k = k0 + ty + p * 8;
            int n = n0 + tx;
            tile[ty + p * 8][tx] = (n < HD) ? f2bf(W1[k * HD + n]) : (unsigned short)0;
        }
        __syncthreads();
#pragma unroll
        for (int p = 0; p < 4; p++) {
            int n = n0 + ty + p * 8;
            int k = k0 + tx;
            w1t[n * 512 + k] = tile[tx][ty + p * 8];
        }
    } else {                                      // W2t[n*2080 + cch*52+kk] = W2[(cch*49+kk)*512+n]
        int blk = b - 6784;                       // 62 kt x 16 nt
        int kt = blk % 62, nt = blk / 62;
        int k0 = kt * 32, n0 = nt * 32;
#pragma unroll
        for (int p = 0; p < 4; p++) {
            int k = k0 + ty + p * 8;
            int n = n0 + tx;
            tile[ty + p * 8][tx] = (k < HD) ? f2bf(W2[k * 512 + n]) : (unsigned short)0;
        }
        __syncthreads();
#pragma unroll
        for (int p = 0; p < 4; p++) {
            int n = n0 + ty + p * 8;
            int k = k0 + tx;
            if (k < HD) {
                int cch = k / 49, kk = k - cch * 49;
                w2t[n * K2 + cch * CPAD + kk] = tile[tx][ty + p * 8];
            }
        }
    }
}

// ---------- GEMM1: h_blk[(b2*40+cch)*720 + sp][52] = x @ W1 + b1 (blocked-layout epilogue) ----------
__global__ __launch_bounds__(256) void gemm1_blk(
    const unsigned short* __restrict__ A,
    const unsigned short* __restrict__ Bt,
    const float* __restrict__ bias,
    unsigned short* __restrict__ h_blk)
{
    __shared__ unsigned short sA[128 * 32];
    __shared__ unsigned short sB[128 * 32];
    const int lda = D_IN, ldb = D_IN, K = D_IN, nbx = HDP / 128;

    int bid = blockIdx.x;
    int bx = bid % nbx, by = bid / nbx;
    int t    = threadIdx.x;
    int w    = t >> 6;
    int lane = t & 63;
    int quad = lane >> 4;
    int l16  = lane & 15;
    int row0 = by * 128, col0 = bx * 128;
    int wr = (w >> 1) * 64, wc = (w & 1) * 64;

    const unsigned short* Ag = A  + (size_t)(row0 + (t >> 2)) * lda + (t & 3) * 8;
    const unsigned short* Bg = Bt + (size_t)(col0 + (t >> 2)) * ldb + (t & 3) * 8;
    unsigned short* lA0 = sA + t * 8;
    unsigned short* lA1 = sA + 2048 + t * 8;
    unsigned short* lB0 = sB + t * 8;
    unsigned short* lB1 = sB + 2048 + t * 8;

    f32x4 acc[4][4] = {};

    for (int k0 = 0; k0 < K; k0 += 32) {
        gl_lds16(Ag + k0, lA0);
        gl_lds16(Ag + (size_t)64 * lda + k0, lA1);
        gl_lds16(Bg + k0, lB0);
        gl_lds16(Bg + (size_t)64 * ldb + k0, lB1);
        __syncthreads();

        bf16x8 a[4], bfr[4];
#pragma unroll
        for (int i = 0; i < 4; i++)
            a[i] = *(const bf16x8*)(sA + (wr + i * 16 + l16) * 32 + quad * 8);
#pragma unroll
        for (int j = 0; j < 4; j++)
            bfr[j] = *(const bf16x8*)(sB + (wc + j * 16 + l16) * 32 + quad * 8);
#pragma unroll
        for (int i = 0; i < 4; i++)
#pragma unroll
            for (int j = 0; j < 4; j++)
                acc[i][j] = __builtin_amdgcn_mfma_f32_16x16x32_bf16(a[i], bfr[j], acc[i][j], 0, 0, 0);
        __syncthreads();
    }

    // row terms: addr = b2*1497600 + cch*37440 + sp*52 + kk
    int rowterm[16];
#pragma unroll
    for (int i = 0; i < 4; i++)
#pragma unroll
        for (int r = 0; r < 4; r++) {
            int row = row0 + wr + i * 16 + quad * 4 + r;
            int bb = row / NVECS;
            int sp = row - bb * NVECS;
            rowterm[i * 4 + r] = bb * (CCH * NVECS * CPAD) + sp * CPAD;
        }

#pragma unroll
    for (int j = 0; j < 4; j++) {
        int col = col0 + wc + j * 16 + l16;       // natural: col = cch*49 + kk
        if (col < HD) {
            int cch = col / 49, kk = col - cch * 49;
            int colterm = cch * (NVECS * CPAD) + kk;
            float bv = bias[col];
#pragma unroll
            for (int i = 0; i < 4; i++)
#pragma unroll
                for (int r = 0; r < 4; r++)
                    h_blk[(size_t)rowterm[i * 4 + r] + colterm] = f2bf(acc[i][j][r] + bv);
        }
    }
}

// ---------- fused fold+norm+relu+unfold: h_blk -> uf (M x 2080, 52-padded) ----------
// block = (b2, cch, half): stages h_blk lh-rows [8*half, 8*half+12) -> LDS,
// computes y rows [27*half, 27*half + (half?33:31)) in LDS (norm+relu),
// then unfold-gathers rows lh in [10*half, 10*half+10) and writes uf.
// Fold math is fully unrolled & branch-free (NO runtime-indexed arrays -> no scratch).
__global__ __launch_bounds__(256) void fold_unfold(
    const unsigned short* __restrict__ h_blk,
    unsigned short* __restrict__ uf)
{
    __shared__ unsigned short h_lds[12 * 36 * CPAD];  // 44,928 B
    __shared__ unsigned short y_lds[33 * WW];         //  7,128 B
    int bid  = blockIdx.x;                            // 16*40*2 = 1280
    int half = bid & 1;
    int cch  = (bid >> 1) % CCH;
    int b2   = bid / (CCH * 2);
    int tid  = threadIdx.x;

    int lh_base = half ? 8 : 0;
    int y0 = half ? 27 : 0;
    int ny = half ? 33 : 31;

    // stage 12 contiguous lh-strips of h_blk
    const su4* hsrc = (const su4*)(h_blk +
        ((size_t)(b2 * CCH + cch) * NVECS + lh_base * 36) * CPAD);
    su4* hd = (su4*)h_lds;
    for (int i = tid; i < 12 * 36 * CPAD / 4; i += 256)
        hd[i] = hsrc[i];
    __syncthreads();

    // fold + normalize + relu into y_lds (branch-free 3x3 closed form)
    for (int idx = tid; idx < ny * WW; idx += 256) {
        int rr = idx / WW, c = idx - rr * WW;
        int r  = y0 + rr;
        int rp = r + 3, cp = c + 3;
        int q1 = rp / 3, rem1 = rp - q1 * 3;
        int q2 = cp / 3, rem2 = cp - q2 * 3;

        // row candidates: (lh = q1-i, k1 = rem1+3i), i = 0,1,2
        bool rv0 = (q1 <= 19);
        bool rv2 = (rem1 == 0) & (q1 >= 2);
        int sl0 = q1 - lh_base, sl1 = sl0 - 1, sl2 = sl0 - 2;
        int rofs0 = rem1 * 7, rofs1 = rofs0 + 21, rofs2 = rofs0 + 42;
        // col candidates: (lw = q2-j, k2 = rem2+3j), j = 0,1,2
        bool cv0 = (q2 <= 35);
        bool cv2 = (rem2 == 0) & (q2 >= 2);
        int lw0 = q2, lw1 = q2 - 1, lw2 = q2 - 2;

        int n1 = 1 + (int)rv0 + (int)rv2;
        int n2 = 1 + (int)cv0 + (int)cv2;

        float s = 0.0f;
#define FTERM(vr, sl, rofs, vc, lw, cofs) {                                   \
        bool vv = (vr) & (vc);                                                \
        int ad = vv ? (((sl) * 36 + (lw)) * CPAD + (rofs) + (cofs)) : 0;      \
        float val = bf2f(h_lds[ad]);                                          \
        s += vv ? val : 0.0f; }
        FTERM(rv0,  sl0, rofs0, cv0,  lw0, rem2)
        FTERM(rv0,  sl0, rofs0, true, lw1, rem2 + 3)
        FTERM(rv0,  sl0, rofs0, cv2,  lw2, rem2 + 6)
        FTERM(true, sl1, rofs1, cv0,  lw0, rem2)
        FTERM(true, sl1, rofs1, true, lw1, rem2 + 3)
        FTERM(true, sl1, rofs1, cv2,  lw2, rem2 + 6)
        FTERM(rv2,  sl2, rofs2, cv0,  lw0, rem2)
        FTERM(rv2,  sl2, rofs2, true, lw1, rem2 + 3)
        FTERM(rv2,  sl2, rofs2, cv2,  lw2, rem2 + 6)
#undef FTERM
        y_lds[idx] = f2bf(fmaxf(s / (float)(n1 * n2), 0.0f));
    }
    __syncthreads();

    // unfold: 360 rows (lh in [10*half, 10*half+10) x lw in [0,36)), 13 su4 each
    int lh0 = 10 * half;
    for (int i = tid; i < 360 * 13; i += 256) {
        int ri = i / 13, q = i - ri * 13;
        int lh = lh0 + ri / 36;
        int lw = ri % 36;
        int rb = 3 * lh - 3, cb = 3 * lw - 3;
        int j0 = q * 4;
        su4 o;
#pragma unroll
        for (int e = 0; e < 4; e++) {
            int j = j0 + e;
            unsigned short val = 0;
            if (j < 49) {
                int k1 = j / 7, k2 = j - k1 * 7;
                int r = rb + k1, cc = cb + k2;
                if ((unsigned)r < (unsigned)HH && (unsigned)cc < (unsigned)WW)
                    val = y_lds[(r - y0) * WW + cc];
            }
            ((unsigned short*)&o)[e] = val;
        }
        int row = b2 * NVECS + lh * 36 + lw;
        *(su4*)(uf + (size_t)row * K2 + cch * CPAD + j0) = o;
    }
}

// ---------- GEMM2: out(f32) = uf @ W2t^T + b2   (M=11520, N=512, K=2080) ----------
__global__ __launch_bounds__(256) void gemm2(
    const unsigned short* __restrict__ A,
    const unsigned short* __restrict__ Bt,
    const float* __restrict__ bias,
    float* __restrict__ C)
{
    __shared__ unsigned short sA[128 * 32];
    __shared__ unsigned short sB[128 * 32];
    const int lda = K2, ldb = K2, ldc = D_IN, K = K2, nbx = D_IN / 128;

    int bid = blockIdx.x;
    int bx = bid % nbx, by = bid / nbx;
    int t    = threadIdx.x;
    int w    = t >> 6;
    int lane = t & 63;
    int quad = lane >> 4;
    int l16  = lane & 15;
    int row0 = by * 128, col0 = bx * 128;
    int wr = (w >> 1) * 64, wc = (w & 1) * 64;

    const unsigned short* Ag = A  + (size_t)(row0 + (t >> 2)) * lda + (t & 3) * 8;
    const unsigned short* Bg = Bt + (size_t)(col0 + (t >> 2)) * ldb + (t & 3) * 8;
    unsigned short* lA0 = sA + t * 8;
    unsigned short* lA1 = sA + 2048 + t * 8;
    unsigned short* lB0 = sB + t * 8;
    unsigned short* lB1 = sB + 2048 + t * 8;

    f32x4 acc[4][4] = {};

    for (int k0 = 0; k0 < K; k0 += 32) {
        gl_lds16(Ag + k0, lA0);
        gl_lds16(Ag + (size_t)64 * lda + k0, lA1);
        gl_lds16(Bg + k0, lB0);
        gl_lds16(Bg + (size_t)64 * ldb + k0, lB1);
        __syncthreads();

        bf16x8 a[4], bfr[4];
#pragma unroll
        for (int i = 0; i < 4; i++)
            a[i] = *(const bf16x8*)(sA + (wr + i * 16 + l16) * 32 + quad * 8);
#pragma unroll
        for (int j = 0; j < 4; j++)
            bfr[j] = *(const bf16x8*)(sB + (wc + j * 16 + l16) * 32 + quad * 8);
#pragma unroll
        for (int i = 0; i < 4; i++)
#pragma unroll
            for (int j = 0; j < 4; j++)
                acc[i][j] = __builtin_amdgcn_mfma_f32_16x16x32_bf16(a[i], bfr[j], acc[i][j], 0, 0, 0);
        __syncthreads();
    }

#pragma unroll
    for (int j = 0; j < 4; j++) {
        int col = col0 + wc + j * 16 + l16;
        float bv = bias[col];
#pragma unroll
        for (int i = 0; i < 4; i++) {
            int rbase = row0 + wr + i * 16 + quad * 4;
#pragma unroll
            for (int r = 0; r < 4; r++)
                C[(size_t)(rbase + r) * ldc + col] = acc[i][j][r] + bv;
        }
    }
}

// ---------- launch ----------
extern "C" void kernel_launch(void* const* d_in, const int* in_sizes, int n_in,
                              void* d_out, int out_size, void* d_ws, size_t ws_size,
                              hipStream_t stream) {
    const float* x   = (const float*)d_in[0];
    const float* W1  = (const float*)d_in[1];
    const float* b1  = (const float*)d_in[2];
    const float* W2  = (const float*)d_in[3];
    const float* b2f = (const float*)d_in[4];
    float* out = (float*)d_out;

    unsigned short* ws    = (unsigned short*)d_ws;
    unsigned short* xb    = ws;                                 // 11520*512
    unsigned short* h_blk = xb + (size_t)M_ROWS * D_IN;         // 23,961,600
    unsigned short* uf    = h_blk + (size_t)M_ROWS * K2;        // 23,961,600
    unsigned short* w1t   = uf + (size_t)M_ROWS * K2;           // 2048*512
    unsigned short* w2t   = w1t + (size_t)HDP * D_IN;           // 512*2080

    // 1. prep: conv x, pack W1t, pack W2t (one dispatch)
    hipLaunchKernelGGL(prep, dim3(7776), dim3(256), 0, stream, x, W1, W2, xb, w1t, w2t);

    // 2. GEMM1 -> h_blk (blocked fold-friendly layout)
    hipLaunchKernelGGL(gemm1_blk, dim3((M_ROWS / 128) * (HDP / 128)), dim3(256), 0, stream,
                       xb, w1t, b1, h_blk);

    // 3. fused fold + normalize + relu + unfold -> uf (52-padded)
    hipLaunchKernelGGL(fold_unfold, dim3(B2C * CCH * 2), dim3(256), 0, stream, h_blk, uf);

    // 4. GEMM2 -> out (f32)
    hipLaunchKernelGGL(gemm2, dim3((M_ROWS / 128) * (D_IN / 128)), dim3(256), 0, stream,
                       uf, w2t, b2f, out);
}